// Round 1
// baseline (494.326 us; speedup 1.0000x reference)
//
#include <hip/hip_runtime.h>

// TriangleAttentionStartingNode  B=1, N=256, C_Z=128, H=4, D=32, TOTAL=128
// Round 1: correct fp32 baseline, 3 kernels:
//   1) ln_proj: LN fused into GEMM [65536x128]@[128x516] -> Q,K,V,G,Bias
//   2) attn:    per (i,h,jtile) flash-style attention -> gvals = G * softmax(QK^T+bias) @ V
//   3) out_proj: gvals @ Wo + bo

#define NSEQ 256
#define QSCALE 0.17677669529663687f  // 1/sqrt(32)

__device__ __forceinline__ float4 ld4(const float* p) { return *(const float4*)p; }
__device__ __forceinline__ void st4(float* p, float4 v) { *(float4*)p = v; }

// ---------------------------------------------------------------------------
// Stage 1: LayerNorm + Q/K/V/G/Bias projections.
// grid (9, 1024): blockIdx.x = N-tile (9 tiles of 64 cols over 516),
//                 blockIdx.y = M-tile (64 positions). block = 256 threads.
// LDS: As[k][m] (128x68) normalized-x transposed; Bsm[k][n] (128x68) weights
//      (Bsm region first reused as raw-x staging buffer [64][132]).
// ---------------------------------------------------------------------------
__global__ __launch_bounds__(256) void ln_proj_kernel(
    const float* __restrict__ x, const float* __restrict__ gamma, const float* __restrict__ beta,
    const float* __restrict__ Wq, const float* __restrict__ Wk, const float* __restrict__ Wv,
    const float* __restrict__ Wb, const float* __restrict__ Wg, const float* __restrict__ bg,
    float* __restrict__ Qws, float* __restrict__ Kws, float* __restrict__ Vws,
    float* __restrict__ Gws, float* __restrict__ Bws)
{
    __shared__ float As[128 * 68];
    __shared__ float Bsm[128 * 68];   // >= 64*132 floats, reused as raw x first
    const int t  = threadIdx.x;
    const int nt = blockIdx.x;        // 0..8
    const int pt = blockIdx.y;        // 0..1023
    const int p0 = pt * 64;

    // ---- load raw x tile [64][132-pad] into Bsm ----
    float* rawx = Bsm;
#pragma unroll
    for (int r = 0; r < 8; ++r) {
        int e = r * 256 + t;                 // 2048 float4s
        int m = e >> 5, k4 = (e & 31) * 4;
        st4(&rawx[m * 132 + k4], ld4(&x[(p0 + m) * 128 + k4]));
    }
    __syncthreads();

    // ---- LayerNorm rows -> As[c][m] (transposed) ----
    {
        const int row = t >> 2, q = t & 3;   // 4 threads per row, 32 ch each
        const float* rp = &rawx[row * 132 + q * 32];
        float4 v[8];
        float sum = 0.f, ssq = 0.f;
#pragma unroll
        for (int ii = 0; ii < 8; ++ii) {
            v[ii] = ld4(rp + ii * 4);
            sum += v[ii].x + v[ii].y + v[ii].z + v[ii].w;
            ssq += v[ii].x * v[ii].x + v[ii].y * v[ii].y + v[ii].z * v[ii].z + v[ii].w * v[ii].w;
        }
        sum += __shfl_xor(sum, 1); ssq += __shfl_xor(ssq, 1);
        sum += __shfl_xor(sum, 2); ssq += __shfl_xor(ssq, 2);
        float mu   = sum * (1.f / 128.f);
        float var  = ssq * (1.f / 128.f) - mu * mu;
        float rstd = rsqrtf(var + 1e-5f);
#pragma unroll
        for (int ii = 0; ii < 8; ++ii) {
            int c = q * 32 + ii * 4;
            float4 g4 = ld4(&gamma[c]);
            float4 b4 = ld4(&beta[c]);
            As[(c + 0) * 68 + row] = (v[ii].x - mu) * rstd * g4.x + b4.x;
            As[(c + 1) * 68 + row] = (v[ii].y - mu) * rstd * g4.y + b4.y;
            As[(c + 2) * 68 + row] = (v[ii].z - mu) * rstd * g4.z + b4.z;
            As[(c + 3) * 68 + row] = (v[ii].w - mu) * rstd * g4.w + b4.w;
        }
    }
    __syncthreads();   // all rawx reads done before Bsm is overwritten

    // ---- load weight tile into Bsm[k][n] ----
    const int c0 = nt * 64;
#pragma unroll
    for (int r = 0; r < 8; ++r) {
        int e = r * 256 + t;                 // 2048 float4s
        int k = e >> 4, cl4 = (e & 15) * 4;
        int c = c0 + cl4;
        float4 w = make_float4(0.f, 0.f, 0.f, 0.f);
        if (c < 512) {
            const float* Wm = (c < 128) ? Wq : (c < 256) ? Wk : (c < 384) ? Wv : Wg;
            w = ld4(&Wm[k * 128 + (c & 127)]);
        } else if (c == 512) {
            w = ld4(&Wb[k * 4]);             // Wb row k: 4 floats
        }
        st4(&Bsm[k * 68 + cl4], w);
    }
    __syncthreads();

    // ---- 64x64 GEMM, 4x4 per thread ----
    const int tx = t & 15, ty = t >> 4;
    float acc[4][4] = {{0.f}};
#pragma unroll 8
    for (int k = 0; k < 128; ++k) {
        float4 a4 = ld4(&As[k * 68 + ty * 4]);
        float4 b4 = ld4(&Bsm[k * 68 + tx * 4]);
        float av[4] = {a4.x, a4.y, a4.z, a4.w};
        float bv[4] = {b4.x, b4.y, b4.z, b4.w};
#pragma unroll
        for (int mi = 0; mi < 4; ++mi)
#pragma unroll
            for (int ni = 0; ni < 4; ++ni)
                acc[mi][ni] += av[mi] * bv[ni];
    }

    // ---- epilogue: scatter per class ----
#pragma unroll
    for (int mi = 0; mi < 4; ++mi) {
        int p = p0 + ty * 4 + mi;
        int i = p >> 8, j = p & 255;
        if (nt < 8) {
            int cb = c0 + tx * 4;
            int cc = cb & 127;
            int hh = cc >> 5, d0 = cc & 31;
            int off = ((i * 4 + hh) * 256 + j) * 32 + d0;
            float4 v = make_float4(acc[mi][0], acc[mi][1], acc[mi][2], acc[mi][3]);
            int cls = c0 >> 7;
            if (cls == 0) {
                v.x *= QSCALE; v.y *= QSCALE; v.z *= QSCALE; v.w *= QSCALE;
                st4(&Qws[off], v);
            } else if (cls == 1) {
                st4(&Kws[off], v);
            } else if (cls == 2) {
                st4(&Vws[off], v);
            } else {
                float4 bg4 = ld4(&bg[cc]);
                v.x = 1.f / (1.f + __expf(-(v.x + bg4.x)));
                v.y = 1.f / (1.f + __expf(-(v.y + bg4.y)));
                v.z = 1.f / (1.f + __expf(-(v.z + bg4.z)));
                v.w = 1.f / (1.f + __expf(-(v.w + bg4.w)));
                st4(&Gws[off], v);
            }
        } else {
#pragma unroll
            for (int ni = 0; ni < 4; ++ni) {
                int c = 512 + tx * 4 + ni;
                if (c < 516) {
                    int hh = c - 512;
                    Bws[(hh * 256 + i) * 256 + j] = acc[mi][ni];  // [h][n1][n2]
                }
            }
        }
    }
}

// ---------------------------------------------------------------------------
// Stage 2: attention. grid = 4096 blocks: bid = i*16 + h*4 + jt.
// Block handles queries j in [jt*64, jt*64+64) of head (i,h); loops k-tiles
// of 64. No max-subtraction (scores bounded ~ +/-2): P = exp(S+bias),
// O = (P@V)/sum(P). Output gvals[p][h*32+d] = G * O.
// ---------------------------------------------------------------------------
__global__ __launch_bounds__(256) void attn_kernel(
    const float* __restrict__ Qws, const float* __restrict__ Kws, const float* __restrict__ Vws,
    const float* __restrict__ Gws, const float* __restrict__ Bws, float* __restrict__ gvals)
{
    __shared__ float Ql[64 * 36];
    __shared__ float Kt[64 * 36];
    __shared__ float Vt[64 * 36];
    __shared__ float Pt[64 * 68];   // [k][j] transposed
    const int t   = threadIdx.x;
    const int bid = blockIdx.x;
    const int i = bid >> 4, h = (bid >> 2) & 3, jt = bid & 3;
    const int tx = t & 15, ty = t >> 4;

    const float* Qb = Qws + ((i * 4 + h) * 256 + jt * 64) * 32;
    const float* Kb = Kws + ((i * 4 + h) * 256) * 32;
    const float* Vb = Vws + ((i * 4 + h) * 256) * 32;
    const float* Bb = Bws + (h * 256 + jt * 64) * 256;

#pragma unroll
    for (int r = 0; r < 2; ++r) {
        int e = r * 256 + t; int row = e >> 3, d4 = (e & 7) * 4;
        st4(&Ql[row * 36 + d4], ld4(Qb + row * 32 + d4));
    }

    float o0[4] = {0.f, 0.f, 0.f, 0.f};
    float o1[4] = {0.f, 0.f, 0.f, 0.f};
    float lsum[4] = {0.f, 0.f, 0.f, 0.f};

    for (int kt = 0; kt < 4; ++kt) {
        __syncthreads();                       // prior iter done with Kt/Vt/Pt
        const int k0 = kt * 64;
#pragma unroll
        for (int r = 0; r < 2; ++r) {
            int e = r * 256 + t; int row = e >> 3, d4 = (e & 7) * 4;
            st4(&Kt[row * 36 + d4], ld4(Kb + (k0 + row) * 32 + d4));
            st4(&Vt[row * 36 + d4], ld4(Vb + (k0 + row) * 32 + d4));
        }
        __syncthreads();

        // S = Q K^T  (4x4 per thread, dot over d=32)
        float s[4][4] = {{0.f}};
#pragma unroll
        for (int d4 = 0; d4 < 32; d4 += 4) {
            float qa[4][4], ka[4][4];
#pragma unroll
            for (int m = 0; m < 4; ++m) {
                float4 qv = ld4(&Ql[(ty * 4 + m) * 36 + d4]);
                qa[m][0] = qv.x; qa[m][1] = qv.y; qa[m][2] = qv.z; qa[m][3] = qv.w;
            }
#pragma unroll
            for (int n = 0; n < 4; ++n) {
                float4 kv = ld4(&Kt[(tx * 4 + n) * 36 + d4]);
                ka[n][0] = kv.x; ka[n][1] = kv.y; ka[n][2] = kv.z; ka[n][3] = kv.w;
            }
#pragma unroll
            for (int m = 0; m < 4; ++m)
#pragma unroll
                for (int n = 0; n < 4; ++n)
#pragma unroll
                    for (int e4 = 0; e4 < 4; ++e4)
                        s[m][n] += qa[m][e4] * ka[n][e4];
        }

        // P = exp(S + bias); accumulate row sums; write P^T to LDS
#pragma unroll
        for (int m = 0; m < 4; ++m) {
            float4 bv = ld4(Bb + (ty * 4 + m) * 256 + k0 + tx * 4);
            float pb0 = __expf(s[m][0] + bv.x);
            float pb1 = __expf(s[m][1] + bv.y);
            float pb2 = __expf(s[m][2] + bv.z);
            float pb3 = __expf(s[m][3] + bv.w);
            lsum[m] += pb0 + pb1 + pb2 + pb3;
            Pt[(tx * 4 + 0) * 68 + ty * 4 + m] = pb0;
            Pt[(tx * 4 + 1) * 68 + ty * 4 + m] = pb1;
            Pt[(tx * 4 + 2) * 68 + ty * 4 + m] = pb2;
            Pt[(tx * 4 + 3) * 68 + ty * 4 + m] = pb3;
        }
        __syncthreads();

        // O += P @ V  (thread: rows ty*4..+3, cols d = tx and tx+16)
#pragma unroll 4
        for (int k = 0; k < 64; ++k) {
            float4 pv = ld4(&Pt[k * 68 + ty * 4]);
            float vv0 = Vt[k * 36 + tx];
            float vv1 = Vt[k * 36 + tx + 16];
            o0[0] += pv.x * vv0; o1[0] += pv.x * vv1;
            o0[1] += pv.y * vv0; o1[1] += pv.y * vv1;
            o0[2] += pv.z * vv0; o1[2] += pv.z * vv1;
            o0[3] += pv.w * vv0; o1[3] += pv.w * vv1;
        }
    }

    // full row sums over k (reduce across the 16 tx lanes)
#pragma unroll
    for (int m = 0; m < 4; ++m) {
        lsum[m] += __shfl_xor(lsum[m], 1);
        lsum[m] += __shfl_xor(lsum[m], 2);
        lsum[m] += __shfl_xor(lsum[m], 4);
        lsum[m] += __shfl_xor(lsum[m], 8);
    }

#pragma unroll
    for (int m = 0; m < 4; ++m) {
        int j = jt * 64 + ty * 4 + m;
        float rl = 1.f / lsum[m];
        int gb = ((i * 4 + h) * 256 + j) * 32;
        float g0 = Gws[gb + tx];
        float g1 = Gws[gb + tx + 16];
        float* dst = gvals + (i * 256 + j) * 128 + h * 32;
        dst[tx]      = g0 * o0[m] * rl;
        dst[tx + 16] = g1 * o1[m] * rl;
    }
}

// ---------------------------------------------------------------------------
// Stage 3: out = gvals @ Wo + bo.  grid (2, 1024), block 256, 64x64 tiles.
// ---------------------------------------------------------------------------
__global__ __launch_bounds__(256) void out_proj_kernel(
    const float* __restrict__ A, const float* __restrict__ Wo, const float* __restrict__ bo,
    float* __restrict__ out)
{
    __shared__ float As[128 * 68];
    __shared__ float Bsm[128 * 68];
    const int t  = threadIdx.x;
    const int nt = blockIdx.x;   // 0..1
    const int pt = blockIdx.y;
    const int p0 = pt * 64;

    float* rawx = Bsm;
#pragma unroll
    for (int r = 0; r < 8; ++r) {
        int e = r * 256 + t;
        int m = e >> 5, k4 = (e & 31) * 4;
        st4(&rawx[m * 132 + k4], ld4(&A[(p0 + m) * 128 + k4]));
    }
    __syncthreads();
    {
        const int row = t >> 2, q = t & 3;
#pragma unroll
        for (int ii = 0; ii < 8; ++ii) {
            float4 v = ld4(&rawx[row * 132 + q * 32 + ii * 4]);
            int c = q * 32 + ii * 4;
            As[(c + 0) * 68 + row] = v.x;
            As[(c + 1) * 68 + row] = v.y;
            As[(c + 2) * 68 + row] = v.z;
            As[(c + 3) * 68 + row] = v.w;
        }
    }
    __syncthreads();

    const int c0 = nt * 64;
#pragma unroll
    for (int r = 0; r < 8; ++r) {
        int e = r * 256 + t;
        int k = e >> 4, cl4 = (e & 15) * 4;
        st4(&Bsm[k * 68 + cl4], ld4(&Wo[k * 128 + c0 + cl4]));
    }
    __syncthreads();

    const int tx = t & 15, ty = t >> 4;
    float acc[4][4] = {{0.f}};
#pragma unroll 8
    for (int k = 0; k < 128; ++k) {
        float4 a4 = ld4(&As[k * 68 + ty * 4]);
        float4 b4 = ld4(&Bsm[k * 68 + tx * 4]);
        float av[4] = {a4.x, a4.y, a4.z, a4.w};
        float bv[4] = {b4.x, b4.y, b4.z, b4.w};
#pragma unroll
        for (int mi = 0; mi < 4; ++mi)
#pragma unroll
            for (int ni = 0; ni < 4; ++ni)
                acc[mi][ni] += av[mi] * bv[ni];
    }

    float4 bo4 = ld4(&bo[c0 + tx * 4]);
#pragma unroll
    for (int mi = 0; mi < 4; ++mi) {
        int p = p0 + ty * 4 + mi;
        float4 v = make_float4(acc[mi][0] + bo4.x, acc[mi][1] + bo4.y,
                               acc[mi][2] + bo4.z, acc[mi][3] + bo4.w);
        st4(&out[p * 128 + c0 + tx * 4], v);
    }
}

// ---------------------------------------------------------------------------
extern "C" void kernel_launch(void* const* d_in, const int* in_sizes, int n_in,
                              void* d_out, int out_size, void* d_ws, size_t ws_size,
                              hipStream_t stream) {
    const float* x     = (const float*)d_in[0];
    const float* gamma = (const float*)d_in[1];
    const float* beta  = (const float*)d_in[2];
    const float* Wq    = (const float*)d_in[3];
    const float* Wk    = (const float*)d_in[4];
    const float* Wv    = (const float*)d_in[5];
    const float* Wb    = (const float*)d_in[6];
    const float* Wg    = (const float*)d_in[7];
    const float* bg    = (const float*)d_in[8];
    const float* Wo    = (const float*)d_in[9];
    const float* bo    = (const float*)d_in[10];

    float* ws    = (float*)d_ws;
    float* Qws   = ws;                     // 65536*128
    float* Kws   = Qws + 8388608;
    float* Vws   = Kws + 8388608;
    float* Gws   = Vws + 8388608;
    float* Bws   = Gws + 8388608;          // 4*256*256
    float* gvals = Bws + 262144;           // 65536*128
    // total: 42,205,184 floats = 168.8 MB of d_ws

    ln_proj_kernel<<<dim3(9, 1024), 256, 0, stream>>>(
        x, gamma, beta, Wq, Wk, Wv, Wb, Wg, bg, Qws, Kws, Vws, Gws, Bws);
    attn_kernel<<<dim3(4096), 256, 0, stream>>>(Qws, Kws, Vws, Gws, Bws, gvals);
    out_proj_kernel<<<dim3(2, 1024), 256, 0, stream>>>(gvals, Wo, bo, (float*)d_out);
}

// Round 2
// 239.362 us; speedup vs baseline: 2.0652x; 2.0652x over previous
//
#include <hip/hip_runtime.h>

// TriangleAttentionStartingNode  B=1, N=256, C_Z=128, H=4, D=32, TOTAL=128
// Round 2: full bf16 MFMA pipeline (16x16x32_bf16), 5 kernels:
//   prep:  pack W^T (Q pre-scaled, Wb appended) + Wo^T into MFMA-frag-order bf16
//   ln:    LayerNorm -> xn bf16 [65536][128] (A-frag-ready row-major)
//   proj:  xn @ W -> Q,K,V(row-major),G(sigmoid),Bias  (MFMA, B in LDS frag-order)
//   attn:  per (i,h): softmax(QK^T+bias)V * G -> gvals bf16 (MFMA, flash-style)
//   oproj: gvals @ Wo + bo -> out fp32 (MFMA)

#define QSCALE 0.17677669529663687f  // 1/sqrt(32)

typedef __attribute__((ext_vector_type(8))) short bf16x8;
typedef __attribute__((ext_vector_type(4))) float f32x4;

__device__ __forceinline__ ushort f2bf(float f) {
    uint32_t u = __builtin_bit_cast(uint32_t, f);
    uint32_t r = (u + 0x7FFFu + ((u >> 16) & 1u)) >> 16;  // RNE
    return (ushort)r;
}
__device__ __forceinline__ float bf2f(ushort b) {
    return __builtin_bit_cast(float, ((uint32_t)b) << 16);
}
__device__ __forceinline__ float4 ld4f(const float* p) { return *(const float4*)p; }

// ---------------------------------------------------------------------------
// prep: Wfrag[ct 0..32][ks 0..3][lane 0..63][j 0..7] bf16 where
//   n = ct*16 + (lane&15), k = ks*32 + (lane>>4)*8 + j, value = W^T[n][k].
//   n: 0..127 Wq*QSCALE, 128..255 Wk, 256..383 Wv, 384..511 Wg, 512..515 Wb, else 0.
// WoFrag: same layout with 8 ct over Wo^T.
// grid 328*256 = 83968 = 67584 + 16384 exactly.
// ---------------------------------------------------------------------------
__global__ __launch_bounds__(256) void prep_kernel(
    const float* __restrict__ Wq, const float* __restrict__ Wk, const float* __restrict__ Wv,
    const float* __restrict__ Wb, const float* __restrict__ Wg, const float* __restrict__ Wo,
    ushort* __restrict__ Wfrag, ushort* __restrict__ WoFrag)
{
    int idx = blockIdx.x * 256 + threadIdx.x;
    if (idx < 67584) {
        int j = idx & 7, lane = (idx >> 3) & 63, ks = (idx >> 9) & 3, ct = idx >> 11;
        int n = ct * 16 + (lane & 15);
        int k = ks * 32 + (lane >> 4) * 8 + j;
        float v = 0.f;
        if (n < 128)      v = Wq[k * 128 + n] * QSCALE;
        else if (n < 256) v = Wk[k * 128 + (n - 128)];
        else if (n < 384) v = Wv[k * 128 + (n - 256)];
        else if (n < 512) v = Wg[k * 128 + (n - 384)];
        else if (n < 516) v = Wb[k * 4 + (n - 512)];
        Wfrag[idx] = f2bf(v);
    } else {
        int idx2 = idx - 67584;
        int j = idx2 & 7, lane = (idx2 >> 3) & 63, ks = (idx2 >> 9) & 3, ct = idx2 >> 11;
        int n = ct * 16 + (lane & 15);
        int k = ks * 32 + (lane >> 4) * 8 + j;
        WoFrag[idx2] = f2bf(Wo[k * 128 + n]);
    }
}

// ---------------------------------------------------------------------------
// ln: 512 blocks x 256 thr, 2 threads per row (64 ch each), shfl_xor(1) reduce.
// ---------------------------------------------------------------------------
__global__ __launch_bounds__(256) void ln_kernel(
    const float* __restrict__ x, const float* __restrict__ gamma,
    const float* __restrict__ beta, ushort* __restrict__ xn)
{
    const int t = threadIdx.x;
    const int row = blockIdx.x * 128 + (t >> 1);
    const int half = t & 1;
    const float* rp = x + row * 128 + half * 64;
    float4 v[16];
    float sum = 0.f, ssq = 0.f;
#pragma unroll
    for (int ii = 0; ii < 16; ++ii) {
        v[ii] = ld4f(rp + ii * 4);
        sum += v[ii].x + v[ii].y + v[ii].z + v[ii].w;
        ssq += v[ii].x * v[ii].x + v[ii].y * v[ii].y + v[ii].z * v[ii].z + v[ii].w * v[ii].w;
    }
    sum += __shfl_xor(sum, 1);
    ssq += __shfl_xor(ssq, 1);
    float mu   = sum * (1.f / 128.f);
    float var  = ssq * (1.f / 128.f) - mu * mu;
    float rstd = rsqrtf(var + 1e-5f);

    uint2* op = (uint2*)(xn + row * 128 + half * 64);
#pragma unroll
    for (int ii = 0; ii < 16; ++ii) {
        float4 g4 = ld4f(gamma + half * 64 + ii * 4);
        float4 b4 = ld4f(beta  + half * 64 + ii * 4);
        float a0 = (v[ii].x - mu) * rstd * g4.x + b4.x;
        float a1 = (v[ii].y - mu) * rstd * g4.y + b4.y;
        float a2 = (v[ii].z - mu) * rstd * g4.z + b4.z;
        float a3 = (v[ii].w - mu) * rstd * g4.w + b4.w;
        uint2 u;
        u.x = (uint)f2bf(a0) | ((uint)f2bf(a1) << 16);
        u.y = (uint)f2bf(a2) | ((uint)f2bf(a3) << 16);
        op[ii] = u;
    }
}

// ---------------------------------------------------------------------------
// proj: grid 1024 (64 rows each), 4 waves; wave w = m-tile w (16 rows) x 33
// col-tiles. A-frags direct from global xn (16B/lane). B staged to LDS in
// frag order in 2 phases (17+16 tiles, 69632 B -> 2 blocks/CU).
// Epilogue scatters per class. C-layout: col=lane&15, row=quad*4+reg.
// ---------------------------------------------------------------------------
__global__ __launch_bounds__(256) void proj_kernel(
    const ushort* __restrict__ xn, const ushort* __restrict__ Wfrag, const float* __restrict__ bg,
    ushort* __restrict__ Qg, ushort* __restrict__ Kg, ushort* __restrict__ Vg,
    ushort* __restrict__ Gg, ushort* __restrict__ Bb)
{
    __shared__ ushort Bs[17 * 2048];
    const int t = threadIdx.x;
    const int wave = t >> 6, lane = t & 63, m = lane & 15, quad = lane >> 4;
    const int p0 = blockIdx.x * 64;

    bf16x8 afrag[4];
    const int arow = p0 + wave * 16 + m;
#pragma unroll
    for (int ks = 0; ks < 4; ++ks)
        afrag[ks] = *(const bf16x8*)(xn + arow * 128 + ks * 32 + quad * 8);

    for (int phase = 0; phase < 2; ++phase) {
        const int ctbase = phase * 17;
        const int nct = phase ? 16 : 17;
        __syncthreads();
        const uint4* src = (const uint4*)(Wfrag + ctbase * 2048);
        uint4* dst = (uint4*)Bs;
        for (int r = 0; r < nct; ++r) dst[r * 256 + t] = src[r * 256 + t];
        __syncthreads();

        for (int ctl = 0; ctl < nct; ++ctl) {
            const int ct = ctbase + ctl;
            f32x4 acc = (f32x4){0.f, 0.f, 0.f, 0.f};
#pragma unroll
            for (int ks = 0; ks < 4; ++ks) {
                bf16x8 bfr = ((const bf16x8*)Bs)[(ctl * 4 + ks) * 64 + lane];
                acc = __builtin_amdgcn_mfma_f32_16x16x32_bf16(afrag[ks], bfr, acc, 0, 0, 0);
            }
            if (ct < 32) {
                const int cls = ct >> 3;
                const int np = (ct & 7) * 16 + m;     // 0..127 within class
                const int hh = np >> 5, d = np & 31;
                float bgv = (cls == 3) ? bg[np] : 0.f;
#pragma unroll
                for (int r = 0; r < 4; ++r) {
                    int p = p0 + wave * 16 + quad * 4 + r;   // (n1 = p>>8, n2 = p&255)
                    int off = (((p >> 8) * 4 + hh) * 256 + (p & 255)) * 32 + d;
                    float val = acc[r];
                    if (cls == 0)      Qg[off] = f2bf(val);            // Q pre-scaled via W
                    else if (cls == 1) Kg[off] = f2bf(val);
                    else if (cls == 2) Vg[off] = f2bf(val);
                    else {
                        float z = val + bgv;
                        Gg[off] = f2bf(1.f / (1.f + __expf(-z)));
                    }
                }
            } else {
                if (m < 4) {   // bias cols: h = m; Bias[j=p>>8][k=p&255] per head
#pragma unroll
                    for (int r = 0; r < 4; ++r) {
                        int p = p0 + wave * 16 + quad * 4 + r;
                        Bb[(m * 256 + (p >> 8)) * 256 + (p & 255)] = f2bf(acc[r]);
                    }
                }
            }
        }
    }
}

// ---------------------------------------------------------------------------
// attn: grid 1024 = (i*4+h). 4 waves; wave = 64 q-rows. V staged LDS-transposed
// once. K/Q frags direct from global. exp without max-subtraction (scores
// ~N(0,0.25) -- bounded). P round-trips LDS (stride-72 rows, 16B-aligned) to
// convert C-layout -> A-layout for PV. One __syncthreads total.
// ---------------------------------------------------------------------------
__global__ __launch_bounds__(256) void attn_kernel(
    const ushort* __restrict__ Qg, const ushort* __restrict__ Kg, const ushort* __restrict__ Vg,
    const ushort* __restrict__ Gg, const ushort* __restrict__ Bb, ushort* __restrict__ gvals)
{
    __shared__ ushort Vt[32 * 264];       // V^T [d][k], pad 264
    __shared__ ushort Pl[4][64 * 72];     // per-wave P [j][k], stride 72 (144 B, 16B-aligned)
    const int t = threadIdx.x;
    const int wave = t >> 6, lane = t & 63, m = lane & 15, quad = lane >> 4;
    const int ih = blockIdx.x, i = ih >> 2, h = ih & 3;

    {   // stage V transposed: thread t = key row j, 64B coalesced read
        const ushort* vrow = Vg + ih * 8192 + t * 32;
        union { uint4 q[4]; ushort s[32]; } vv;
#pragma unroll
        for (int qq = 0; qq < 4; ++qq) vv.q[qq] = ((const uint4*)vrow)[qq];
#pragma unroll
        for (int d = 0; d < 32; ++d) Vt[d * 264 + t] = vv.s[d];
    }
    __syncthreads();

    const int j0 = wave * 64;
    bf16x8 qf[4];
#pragma unroll
    for (int jt = 0; jt < 4; ++jt)
        qf[jt] = *(const bf16x8*)(Qg + ih * 8192 + (j0 + jt * 16 + m) * 32 + quad * 8);

    f32x4 O[4][2];
    float lsum[4][4];
#pragma unroll
    for (int jt = 0; jt < 4; ++jt) {
#pragma unroll
        for (int dt = 0; dt < 2; ++dt) O[jt][dt] = (f32x4){0.f, 0.f, 0.f, 0.f};
#pragma unroll
        for (int r = 0; r < 4; ++r) lsum[jt][r] = 0.f;
    }

    for (int kt2 = 0; kt2 < 4; ++kt2) {
        const int k0 = kt2 * 64;
        bf16x8 kf[4];
#pragma unroll
        for (int kk = 0; kk < 4; ++kk)
            kf[kk] = *(const bf16x8*)(Kg + ih * 8192 + (k0 + kk * 16 + m) * 32 + quad * 8);

        f32x4 S[4][4];
#pragma unroll
        for (int jt = 0; jt < 4; ++jt)
#pragma unroll
            for (int kk = 0; kk < 4; ++kk)
                S[jt][kk] = __builtin_amdgcn_mfma_f32_16x16x32_bf16(
                    qf[jt], kf[kk], (f32x4){0.f, 0.f, 0.f, 0.f}, 0, 0, 0);

        // bias + exp + row-sum partials + P^T staging (C-layout: k=m, j=quad*4+r)
        const ushort* bbase = Bb + h * 65536 + k0 + m;
#pragma unroll
        for (int jt = 0; jt < 4; ++jt) {
#pragma unroll
            for (int kk = 0; kk < 4; ++kk) {
#pragma unroll
                for (int r = 0; r < 4; ++r) {
                    int jl = jt * 16 + quad * 4 + r;
                    float bias = bf2f(bbase[(j0 + jl) * 256 + kk * 16]);
                    float p = __expf(S[jt][kk][r] + bias);
                    lsum[jt][r] += p;
                    Pl[wave][jl * 72 + kk * 16 + m] = f2bf(p);
                }
            }
        }
        // PV over this 64-k group (2 chunks of 32)
#pragma unroll
        for (int kc = 0; kc < 2; ++kc) {
            bf16x8 pf[4], vf[2];
#pragma unroll
            for (int jt = 0; jt < 4; ++jt)
                pf[jt] = *(const bf16x8*)(&Pl[wave][(jt * 16 + m) * 72 + kc * 32 + quad * 8]);
#pragma unroll
            for (int dt = 0; dt < 2; ++dt)
                vf[dt] = *(const bf16x8*)(&Vt[(dt * 16 + m) * 264 + k0 + kc * 32 + quad * 8]);
#pragma unroll
            for (int jt = 0; jt < 4; ++jt)
#pragma unroll
                for (int dt = 0; dt < 2; ++dt)
                    O[jt][dt] = __builtin_amdgcn_mfma_f32_16x16x32_bf16(
                        pf[jt], vf[dt], O[jt][dt], 0, 0, 0);
        }
    }

    // finish row sums across the 16 col-lanes (within quad)
#pragma unroll
    for (int jt = 0; jt < 4; ++jt)
#pragma unroll
        for (int r = 0; r < 4; ++r) {
            float s = lsum[jt][r];
            s += __shfl_xor(s, 1); s += __shfl_xor(s, 2);
            s += __shfl_xor(s, 4); s += __shfl_xor(s, 8);
            lsum[jt][r] = 1.f / s;
        }

    // epilogue: gvals[(i*256+j)][h*32+d] = G * O / lsum
#pragma unroll
    for (int jt = 0; jt < 4; ++jt) {
#pragma unroll
        for (int r = 0; r < 4; ++r) {
            int j = j0 + jt * 16 + quad * 4 + r;
#pragma unroll
            for (int dt = 0; dt < 2; ++dt) {
                int d = dt * 16 + m;
                float g = bf2f(Gg[ih * 8192 + j * 32 + d]);
                float ov = O[jt][dt][r] * lsum[jt][r] * g;
                gvals[(i * 256 + j) * 128 + h * 32 + d] = f2bf(ov);
            }
        }
    }
}

// ---------------------------------------------------------------------------
// oproj: gvals @ Wo + bo -> out fp32. grid 1024 x 64 rows, B (32 KB) in LDS.
// ---------------------------------------------------------------------------
__global__ __launch_bounds__(256) void oproj_kernel(
    const ushort* __restrict__ gvals, const ushort* __restrict__ WoFrag,
    const float* __restrict__ bo, float* __restrict__ out)
{
    __shared__ ushort Bs[8 * 2048];
    const int t = threadIdx.x;
    const int wave = t >> 6, lane = t & 63, m = lane & 15, quad = lane >> 4;
    const int p0 = blockIdx.x * 64;
    {
        const uint4* src = (const uint4*)WoFrag;
        uint4* dst = (uint4*)Bs;
#pragma unroll
        for (int r = 0; r < 8; ++r) dst[r * 256 + t] = src[r * 256 + t];
    }
    bf16x8 afrag[4];
    const int arow = p0 + wave * 16 + m;
#pragma unroll
    for (int ks = 0; ks < 4; ++ks)
        afrag[ks] = *(const bf16x8*)(gvals + arow * 128 + ks * 32 + quad * 8);
    __syncthreads();

#pragma unroll
    for (int ct = 0; ct < 8; ++ct) {
        f32x4 acc = (f32x4){0.f, 0.f, 0.f, 0.f};
#pragma unroll
        for (int ks = 0; ks < 4; ++ks) {
            bf16x8 bfr = ((const bf16x8*)Bs)[(ct * 4 + ks) * 64 + lane];
            acc = __builtin_amdgcn_mfma_f32_16x16x32_bf16(afrag[ks], bfr, acc, 0, 0, 0);
        }
        float bov = bo[ct * 16 + m];
#pragma unroll
        for (int r = 0; r < 4; ++r) {
            int p = p0 + wave * 16 + quad * 4 + r;
            out[p * 128 + ct * 16 + m] = acc[r] + bov;
        }
    }
}

// ---------------------------------------------------------------------------
extern "C" void kernel_launch(void* const* d_in, const int* in_sizes, int n_in,
                              void* d_out, int out_size, void* d_ws, size_t ws_size,
                              hipStream_t stream) {
    const float* x     = (const float*)d_in[0];
    const float* gamma = (const float*)d_in[1];
    const float* beta  = (const float*)d_in[2];
    const float* Wq    = (const float*)d_in[3];
    const float* Wk    = (const float*)d_in[4];
    const float* Wv    = (const float*)d_in[5];
    const float* Wb    = (const float*)d_in[6];
    const float* Wg    = (const float*)d_in[7];
    const float* bg    = (const float*)d_in[8];
    const float* Wo    = (const float*)d_in[9];
    const float* bo    = (const float*)d_in[10];

    ushort* ws     = (ushort*)d_ws;
    ushort* Wfrag  = ws;                    // 67584
    ushort* WoFrag = Wfrag + 67584;         // 16384
    ushort* xn     = WoFrag + 16384;        // 8388608
    ushort* Qg     = xn + 8388608;          // 8388608 each: [ih][n2][d] bf16
    ushort* Kg     = Qg + 8388608;
    ushort* Vg     = Kg + 8388608;
    ushort* Gg     = Vg + 8388608;
    ushort* Bbuf   = Gg + 8388608;          // 262144: [h][j][k] bf16
    ushort* gvals  = Bbuf + 262144;         // 8388608
    // total ~101 MB of d_ws

    prep_kernel<<<328, 256, 0, stream>>>(Wq, Wk, Wv, Wb, Wg, Wo, Wfrag, WoFrag);
    ln_kernel<<<512, 256, 0, stream>>>(x, gamma, beta, xn);
    proj_kernel<<<1024, 256, 0, stream>>>(xn, Wfrag, bg, Qg, Kg, Vg, Gg, Bbuf);
    attn_kernel<<<1024, 256, 0, stream>>>(Qg, Kg, Vg, Gg, Bbuf, gvals);
    oproj_kernel<<<1024, 256, 0, stream>>>(gvals, WoFrag, bo, (float*)d_out);
}

// Round 4
// 189.401 us; speedup vs baseline: 2.6099x; 1.2638x over previous
//
#include <hip/hip_runtime.h>
#include <hip/hip_bf16.h>

// TriangleAttentionStartingNode  B=1, N=256, C_Z=128, H=4, D=32, TOTAL=128
// Round 4 (= R3 + compile fix): operand-swapped MFMA orientations so every
// epilogue/staging stream is vectorized & coalesced:
//   prep:  pack W^T (Q pre-scaled, Wb appended) + Wo^T into MFMA-frag-order bf16
//   ln:    LayerNorm -> xn bf16 [65536][128]
//   proj:  A=W,B=xn -> D[ncol][p]: uint2 stores for Q/K/V/G; bias scattered into
//          attn-fragment-order BbF (coalesced 8B/lane loads in attn)
//   attn:  S^T = K.Q^T (r-axis = k) -> ds_write_b64 P staging; O^T = V^T.P^T
//          (r-axis = d) -> packed G loads + gvals stores, shuffle-free 1/sum
//   oproj: A=Wo,B=gvals -> float4 stores + bo

#define QSCALE 0.17677669529663687f  // 1/sqrt(32)

typedef __attribute__((ext_vector_type(8))) short bf16x8;
typedef __attribute__((ext_vector_type(4))) float f32x4;

__device__ __forceinline__ ushort f2bf(float f) {
    uint32_t u = __builtin_bit_cast(uint32_t, f);
    uint32_t r = (u + 0x7FFFu + ((u >> 16) & 1u)) >> 16;  // RNE
    return (ushort)r;
}
__device__ __forceinline__ float bf2f(ushort b) {
    return __builtin_bit_cast(float, ((uint32_t)b) << 16);
}
__device__ __forceinline__ uint pk2(float a, float b) {   // v_cvt_pk_bf16_f32
    union { __hip_bfloat162 h; uint u; } cv;
    cv.h = __float22bfloat162_rn(make_float2(a, b));
    return cv.u;
}
__device__ __forceinline__ float4 ld4f(const float* p) { return *(const float4*)p; }

// ---------------------------------------------------------------------------
// prep: Wfrag[ct 0..32][ks 0..3][lane 0..63][j 0..7] bf16 where
//   n = ct*16 + (lane&15), k = ks*32 + (lane>>4)*8 + j, value = W^T[n][k].
//   n: 0..127 Wq*QSCALE, 128..255 Wk, 256..383 Wv, 384..511 Wg, 512..515 Wb.
// WoFrag: same layout, 8 ct over Wo^T.   grid 328*256 = 67584 + 16384.
// ---------------------------------------------------------------------------
__global__ __launch_bounds__(256) void prep_kernel(
    const float* __restrict__ Wq, const float* __restrict__ Wk, const float* __restrict__ Wv,
    const float* __restrict__ Wb, const float* __restrict__ Wg, const float* __restrict__ Wo,
    ushort* __restrict__ Wfrag, ushort* __restrict__ WoFrag)
{
    int idx = blockIdx.x * 256 + threadIdx.x;
    if (idx < 67584) {
        int j = idx & 7, lane = (idx >> 3) & 63, ks = (idx >> 9) & 3, ct = idx >> 11;
        int n = ct * 16 + (lane & 15);
        int k = ks * 32 + (lane >> 4) * 8 + j;
        float v = 0.f;
        if (n < 128)      v = Wq[k * 128 + n] * QSCALE;
        else if (n < 256) v = Wk[k * 128 + (n - 128)];
        else if (n < 384) v = Wv[k * 128 + (n - 256)];
        else if (n < 512) v = Wg[k * 128 + (n - 384)];
        else if (n < 516) v = Wb[k * 4 + (n - 512)];
        Wfrag[idx] = f2bf(v);
    } else {
        int idx2 = idx - 67584;
        int j = idx2 & 7, lane = (idx2 >> 3) & 63, ks = (idx2 >> 9) & 3, ct = idx2 >> 11;
        int n = ct * 16 + (lane & 15);
        int k = ks * 32 + (lane >> 4) * 8 + j;
        WoFrag[idx2] = f2bf(Wo[k * 128 + n]);
    }
}

// ---------------------------------------------------------------------------
// ln: 512 blocks x 256 thr, 2 threads per row (64 ch each), shfl_xor(1) reduce.
// ---------------------------------------------------------------------------
__global__ __launch_bounds__(256) void ln_kernel(
    const float* __restrict__ x, const float* __restrict__ gamma,
    const float* __restrict__ beta, ushort* __restrict__ xn)
{
    const int t = threadIdx.x;
    const int row = blockIdx.x * 128 + (t >> 1);
    const int half = t & 1;
    const float* rp = x + row * 128 + half * 64;
    float4 v[16];
    float sum = 0.f, ssq = 0.f;
#pragma unroll
    for (int ii = 0; ii < 16; ++ii) {
        v[ii] = ld4f(rp + ii * 4);
        sum += v[ii].x + v[ii].y + v[ii].z + v[ii].w;
        ssq += v[ii].x * v[ii].x + v[ii].y * v[ii].y + v[ii].z * v[ii].z + v[ii].w * v[ii].w;
    }
    sum += __shfl_xor(sum, 1);
    ssq += __shfl_xor(ssq, 1);
    float mu   = sum * (1.f / 128.f);
    float var  = ssq * (1.f / 128.f) - mu * mu;
    float rstd = rsqrtf(var + 1e-5f);

    uint2* op = (uint2*)(xn + row * 128 + half * 64);
#pragma unroll
    for (int ii = 0; ii < 16; ++ii) {
        float4 g4 = ld4f(gamma + half * 64 + ii * 4);
        float4 b4 = ld4f(beta  + half * 64 + ii * 4);
        float a0 = (v[ii].x - mu) * rstd * g4.x + b4.x;
        float a1 = (v[ii].y - mu) * rstd * g4.y + b4.y;
        float a2 = (v[ii].z - mu) * rstd * g4.z + b4.z;
        float a3 = (v[ii].w - mu) * rstd * g4.w + b4.w;
        uint2 u; u.x = pk2(a0, a1); u.y = pk2(a2, a3);
        op[ii] = u;
    }
}

// ---------------------------------------------------------------------------
// proj: grid 1024 (64 rows each), 4 waves. A = Wfrag (m=ncol), B = xn rows
// (n=p) -> D[ncol][p]: lane&15 = p-within-16, quad*4+r = ncol-within-16.
// Epilogue: r spans 4 consecutive output cols -> uint2 packed stores.
// Bias cols (ct==32, quad==0): scalar scatter into attn-frag-order BbF.
// ---------------------------------------------------------------------------
__global__ __launch_bounds__(256) void proj_kernel(
    const ushort* __restrict__ xn, const ushort* __restrict__ Wfrag, const float* __restrict__ bg,
    ushort* __restrict__ Qg, ushort* __restrict__ Kg, ushort* __restrict__ Vg,
    ushort* __restrict__ Gg, ushort* __restrict__ BbF)
{
    __shared__ ushort Bs[17 * 2048];
    const int t = threadIdx.x;
    const int wave = t >> 6, lane = t & 63, m = lane & 15, quad = lane >> 4;
    const int p0 = blockIdx.x * 64;

    bf16x8 xf[4];
    const int arow = p0 + wave * 16 + m;
#pragma unroll
    for (int ks = 0; ks < 4; ++ks)
        xf[ks] = *(const bf16x8*)(xn + arow * 128 + ks * 32 + quad * 8);

    const int p = p0 + wave * 16 + m;
    const int i = p >> 8, j2 = p & 255;

    for (int phase = 0; phase < 2; ++phase) {
        const int ctbase = phase * 17;
        const int nct = phase ? 16 : 17;
        __syncthreads();
        const uint4* src = (const uint4*)(Wfrag + ctbase * 2048);
        uint4* dst = (uint4*)Bs;
        for (int r = 0; r < nct; ++r) dst[r * 256 + t] = src[r * 256 + t];
        __syncthreads();

        for (int ctl = 0; ctl < nct; ++ctl) {
            const int ct = ctbase + ctl;
            f32x4 acc = (f32x4){0.f, 0.f, 0.f, 0.f};
#pragma unroll
            for (int ks = 0; ks < 4; ++ks) {
                bf16x8 wfr = ((const bf16x8*)Bs)[(ctl * 4 + ks) * 64 + lane];
                acc = __builtin_amdgcn_mfma_f32_16x16x32_bf16(wfr, xf[ks], acc, 0, 0, 0);
            }
            if (ct < 32) {
                const int cls = ct >> 3;
                const int npb = (ct & 7) * 16 + quad * 4;   // class-local col base
                const int hh = npb >> 5, d0 = npb & 31;
                const int off = ((i * 4 + hh) * 256 + j2) * 32 + d0;
                uint2 u;
                if (cls == 3) {
                    float4 bg4 = ld4f(&bg[npb]);
                    float z0 = 1.f / (1.f + __expf(-(acc[0] + bg4.x)));
                    float z1 = 1.f / (1.f + __expf(-(acc[1] + bg4.y)));
                    float z2 = 1.f / (1.f + __expf(-(acc[2] + bg4.z)));
                    float z3 = 1.f / (1.f + __expf(-(acc[3] + bg4.w)));
                    u.x = pk2(z0, z1); u.y = pk2(z2, z3);
                    *(uint2*)(&Gg[off]) = u;
                } else {
                    u.x = pk2(acc[0], acc[1]); u.y = pk2(acc[2], acc[3]);
                    if (cls == 0)      *(uint2*)(&Qg[off]) = u;
                    else if (cls == 1) *(uint2*)(&Kg[off]) = u;
                    else               *(uint2*)(&Vg[off]) = u;
                }
            } else if (quad == 0) {
                // ncol = 512 + r -> h = r.  BbF[h][j>>4][k>>4][((k&15)>>2)*16+(j&15)][k&3]
#pragma unroll
                for (int r = 0; r < 4; ++r) {
                    int addr = (((r * 16 + (i >> 4)) * 16 + (j2 >> 4)) * 64 +
                                ((j2 & 15) >> 2) * 16 + (i & 15)) * 4 + (j2 & 3);
                    BbF[addr] = f2bf(acc[r]);
                }
            }
        }
    }
}

// ---------------------------------------------------------------------------
// attn: grid 1024 = (i*4+h). 4 waves; wave = 64 q-rows.
// S^T = mfma(A=K, B=Q): row=k (r-axis), col=j -> bias via coalesced ushort4
// from BbF; P staged with ds_write_b64. O^T = mfma(A=V^T, B=P): row=d, col=j
// -> packed G loads, packed gvals stores, per-lane 1/sum (j = lane&15).
// ---------------------------------------------------------------------------
__global__ __launch_bounds__(256) void attn_kernel(
    const ushort* __restrict__ Qg, const ushort* __restrict__ Kg, const ushort* __restrict__ Vg,
    const ushort* __restrict__ Gg, const ushort* __restrict__ BbF, ushort* __restrict__ gvals)
{
    __shared__ ushort Vt[32 * 264];       // V^T [d][k]
    __shared__ ushort Pl[4][64 * 72];     // per-wave P [j][k-local 64], stride 72
    const int t = threadIdx.x;
    const int wave = t >> 6, lane = t & 63, m = lane & 15, quad = lane >> 4;
    const int ih = blockIdx.x, i = ih >> 2, h = ih & 3;

    {   // stage V transposed: thread t = key row, 64B coalesced read
        const ushort* vrow = Vg + ih * 8192 + t * 32;
        union { uint4 q[4]; ushort s[32]; } vv;
#pragma unroll
        for (int qq = 0; qq < 4; ++qq) vv.q[qq] = ((const uint4*)vrow)[qq];
#pragma unroll
        for (int d = 0; d < 32; ++d) Vt[d * 264 + t] = vv.s[d];
    }
    __syncthreads();

    const int j0 = wave * 64;
    bf16x8 qf[4];                          // B-frag: lane = j, elems = d
#pragma unroll
    for (int jt = 0; jt < 4; ++jt)
        qf[jt] = *(const bf16x8*)(Qg + ih * 8192 + (j0 + jt * 16 + m) * 32 + quad * 8);

    f32x4 O[4][2];                         // [jt][dt], row=d, col=j
    float lsum[4];
#pragma unroll
    for (int jt = 0; jt < 4; ++jt) {
        O[jt][0] = (f32x4){0.f, 0.f, 0.f, 0.f};
        O[jt][1] = (f32x4){0.f, 0.f, 0.f, 0.f};
        lsum[jt] = 0.f;
    }

    for (int kt2 = 0; kt2 < 4; ++kt2) {
        const int k0 = kt2 * 64;
        bf16x8 kf[4];                      // A-frag: lane = k_, elems = d
#pragma unroll
        for (int kk = 0; kk < 4; ++kk)
            kf[kk] = *(const bf16x8*)(Kg + ih * 8192 + (k0 + kk * 16 + m) * 32 + quad * 8);

#pragma unroll
        for (int jt = 0; jt < 4; ++jt) {
            const int jtg = wave * 4 + jt;
#pragma unroll
            for (int kk = 0; kk < 4; ++kk) {
                f32x4 S = __builtin_amdgcn_mfma_f32_16x16x32_bf16(
                    kf[kk], qf[jt], (f32x4){0.f, 0.f, 0.f, 0.f}, 0, 0, 0);
                const int ktg = kt2 * 4 + kk;
                ushort4 bb = *(const ushort4*)(BbF + (((h * 16 + jtg) * 16 + ktg) * 64 + lane) * 4);
                float pv0 = __expf(S[0] + bf2f(bb.x));
                float pv1 = __expf(S[1] + bf2f(bb.y));
                float pv2 = __expf(S[2] + bf2f(bb.z));
                float pv3 = __expf(S[3] + bf2f(bb.w));
                lsum[jt] += pv0 + pv1 + pv2 + pv3;
                uint2 u; u.x = pk2(pv0, pv1); u.y = pk2(pv2, pv3);
                *(uint2*)(&Pl[wave][(jt * 16 + m) * 72 + kk * 16 + quad * 4]) = u;
            }
        }
#pragma unroll
        for (int kc = 0; kc < 2; ++kc) {
            bf16x8 pf[4], vf[2];
#pragma unroll
            for (int jt = 0; jt < 4; ++jt)   // B-frag: lane = j, elems = k
                pf[jt] = *(const bf16x8*)(&Pl[wave][(jt * 16 + m) * 72 + kc * 32 + quad * 8]);
#pragma unroll
            for (int dt = 0; dt < 2; ++dt)   // A-frag: lane = d, elems = k
                vf[dt] = *(const bf16x8*)(&Vt[(dt * 16 + m) * 264 + k0 + kc * 32 + quad * 8]);
#pragma unroll
            for (int jt = 0; jt < 4; ++jt)
#pragma unroll
                for (int dt = 0; dt < 2; ++dt)
                    O[jt][dt] = __builtin_amdgcn_mfma_f32_16x16x32_bf16(
                        vf[dt], pf[jt], O[jt][dt], 0, 0, 0);
        }
    }

    // total row sums: partials live per-lane at j = lane&15; reduce across quads
#pragma unroll
    for (int jt = 0; jt < 4; ++jt) {
        float s = lsum[jt];
        s += __shfl_xor(s, 16);
        s += __shfl_xor(s, 32);
        lsum[jt] = 1.f / s;
    }

    // epilogue: gvals[(i*256+j)][h*32+d] = G * O / sum  (d = quad*4+r + dt*16)
#pragma unroll
    for (int jt = 0; jt < 4; ++jt) {
        const int j = j0 + jt * 16 + m;
        const float rl = lsum[jt];
#pragma unroll
        for (int dt = 0; dt < 2; ++dt) {
            const int d0 = dt * 16 + quad * 4;
            ushort4 gv = *(const ushort4*)(&Gg[ih * 8192 + j * 32 + d0]);
            float v0 = O[jt][dt][0] * rl * bf2f(gv.x);
            float v1 = O[jt][dt][1] * rl * bf2f(gv.y);
            float v2 = O[jt][dt][2] * rl * bf2f(gv.z);
            float v3 = O[jt][dt][3] * rl * bf2f(gv.w);
            uint2 u; u.x = pk2(v0, v1); u.y = pk2(v2, v3);
            *(uint2*)(&gvals[(i * 256 + j) * 128 + h * 32 + d0]) = u;
        }
    }
}

// ---------------------------------------------------------------------------
// oproj: A = WoFrag, B = gvals rows -> D[ncol][p]; float4 stores + bo.
// ---------------------------------------------------------------------------
__global__ __launch_bounds__(256) void oproj_kernel(
    const ushort* __restrict__ gvals, const ushort* __restrict__ WoFrag,
    const float* __restrict__ bo, float* __restrict__ out)
{
    __shared__ ushort Bs[8 * 2048];
    const int t = threadIdx.x;
    const int wave = t >> 6, lane = t & 63, m = lane & 15, quad = lane >> 4;
    const int p0 = blockIdx.x * 64;
    {
        const uint4* src = (const uint4*)WoFrag;
        uint4* dst = (uint4*)Bs;
#pragma unroll
        for (int r = 0; r < 8; ++r) dst[r * 256 + t] = src[r * 256 + t];
    }
    bf16x8 gf[4];
    const int p = p0 + wave * 16 + m;
#pragma unroll
    for (int ks = 0; ks < 4; ++ks)
        gf[ks] = *(const bf16x8*)(gvals + p * 128 + ks * 32 + quad * 8);
    __syncthreads();

#pragma unroll
    for (int ct = 0; ct < 8; ++ct) {
        f32x4 acc = (f32x4){0.f, 0.f, 0.f, 0.f};
#pragma unroll
        for (int ks = 0; ks < 4; ++ks) {
            bf16x8 wfr = ((const bf16x8*)Bs)[(ct * 4 + ks) * 64 + lane];
            acc = __builtin_amdgcn_mfma_f32_16x16x32_bf16(wfr, gf[ks], acc, 0, 0, 0);
        }
        const int c0 = ct * 16 + quad * 4;
        float4 bov = ld4f(&bo[c0]);
        float4 v = make_float4(acc[0] + bov.x, acc[1] + bov.y,
                               acc[2] + bov.z, acc[3] + bov.w);
        *(float4*)(&out[p * 128 + c0]) = v;
    }
}

// ---------------------------------------------------------------------------
extern "C" void kernel_launch(void* const* d_in, const int* in_sizes, int n_in,
                              void* d_out, int out_size, void* d_ws, size_t ws_size,
                              hipStream_t stream) {
    const float* x     = (const float*)d_in[0];
    const float* gamma = (const float*)d_in[1];
    const float* beta  = (const float*)d_in[2];
    const float* Wq    = (const float*)d_in[3];
    const float* Wk    = (const float*)d_in[4];
    const float* Wv    = (const float*)d_in[5];
    const float* Wb    = (const float*)d_in[6];
    const float* Wg    = (const float*)d_in[7];
    const float* bg    = (const float*)d_in[8];
    const float* Wo    = (const float*)d_in[9];
    const float* bo    = (const float*)d_in[10];

    ushort* ws     = (ushort*)d_ws;
    ushort* Wfrag  = ws;                    // 67584
    ushort* WoFrag = Wfrag + 67584;         // 16384
    ushort* xn     = WoFrag + 16384;        // 8388608
    ushort* Qg     = xn + 8388608;          // [ih][j][d]
    ushort* Kg     = Qg + 8388608;
    ushort* Vg     = Kg + 8388608;
    ushort* Gg     = Vg + 8388608;
    ushort* BbF    = Gg + 8388608;          // 1048576: bias in attn-frag order
    ushort* gvals  = BbF + 1048576;         // 8388608
    // total ~103 MB of d_ws

    prep_kernel<<<328, 256, 0, stream>>>(Wq, Wk, Wv, Wb, Wg, Wo, Wfrag, WoFrag);
    ln_kernel<<<512, 256, 0, stream>>>(x, gamma, beta, xn);
    proj_kernel<<<1024, 256, 0, stream>>>(xn, Wfrag, bg, Qg, Kg, Vg, Gg, BbF);
    attn_kernel<<<1024, 256, 0, stream>>>(Qg, Kg, Vg, Gg, BbF, gvals);
    oproj_kernel<<<1024, 256, 0, stream>>>(gvals, WoFrag, bo, (float*)d_out);
}

// Round 5
// 171.164 us; speedup vs baseline: 2.8880x; 1.1066x over previous
//
#include <hip/hip_runtime.h>
#include <hip/hip_bf16.h>

// TriangleAttentionStartingNode  B=1, N=256, C_Z=128, H=4, D=32, TOTAL=128
// Round 5: occupancy + fusion:
//   prep:  pack W^T (Q pre-scaled, Wb appended) + Wo^T into MFMA-frag-order bf16
//   proj:  LN fused in-register (shfl cross-quad stats); A=W,B=xn -> Q,K,G
//          row-major, V transposed ([ih][d][k]), bias as fp32 in attn-frag order
//   attn:  bias preloaded into MFMA accumulator; no Vt LDS (V^T frags from
//          global); only Pl LDS (36.9 KB -> 4 blocks/CU); zero __syncthreads
//   oproj: A=Wo,B=gvals -> float4 stores + bo

#define QSCALE 0.17677669529663687f  // 1/sqrt(32)

typedef __attribute__((ext_vector_type(8))) short bf16x8;
typedef __attribute__((ext_vector_type(4))) float f32x4;

__device__ __forceinline__ ushort f2bf(float f) {
    uint32_t u = __builtin_bit_cast(uint32_t, f);
    uint32_t r = (u + 0x7FFFu + ((u >> 16) & 1u)) >> 16;  // RNE
    return (ushort)r;
}
__device__ __forceinline__ float bf2f(ushort b) {
    return __builtin_bit_cast(float, ((uint32_t)b) << 16);
}
__device__ __forceinline__ uint pk2(float a, float b) {   // v_cvt_pk_bf16_f32
    union { __hip_bfloat162 h; uint u; } cv;
    cv.h = __float22bfloat162_rn(make_float2(a, b));
    return cv.u;
}
__device__ __forceinline__ float4 ld4f(const float* p) { return *(const float4*)p; }

// ---------------------------------------------------------------------------
// prep: Wfrag[ct 0..32][ks 0..3][lane 0..63][j 0..7] bf16 where
//   n = ct*16 + (lane&15), k = ks*32 + (lane>>4)*8 + j, value = W^T[n][k].
//   n: 0..127 Wq*QSCALE, 128..255 Wk, 256..383 Wv, 384..511 Wg, 512..515 Wb.
// WoFrag: same layout, 8 ct over Wo^T.   grid 328*256 = 67584 + 16384.
// ---------------------------------------------------------------------------
__global__ __launch_bounds__(256) void prep_kernel(
    const float* __restrict__ Wq, const float* __restrict__ Wk, const float* __restrict__ Wv,
    const float* __restrict__ Wb, const float* __restrict__ Wg, const float* __restrict__ Wo,
    ushort* __restrict__ Wfrag, ushort* __restrict__ WoFrag)
{
    int idx = blockIdx.x * 256 + threadIdx.x;
    if (idx < 67584) {
        int j = idx & 7, lane = (idx >> 3) & 63, ks = (idx >> 9) & 3, ct = idx >> 11;
        int n = ct * 16 + (lane & 15);
        int k = ks * 32 + (lane >> 4) * 8 + j;
        float v = 0.f;
        if (n < 128)      v = Wq[k * 128 + n] * QSCALE;
        else if (n < 256) v = Wk[k * 128 + (n - 128)];
        else if (n < 384) v = Wv[k * 128 + (n - 256)];
        else if (n < 512) v = Wg[k * 128 + (n - 384)];
        else if (n < 516) v = Wb[k * 4 + (n - 512)];
        Wfrag[idx] = f2bf(v);
    } else {
        int idx2 = idx - 67584;
        int j = idx2 & 7, lane = (idx2 >> 3) & 63, ks = (idx2 >> 9) & 3, ct = idx2 >> 11;
        int n = ct * 16 + (lane & 15);
        int k = ks * 32 + (lane >> 4) * 8 + j;
        WoFrag[idx2] = f2bf(Wo[k * 128 + n]);
    }
}

// ---------------------------------------------------------------------------
// proj: grid 1024 (64 rows each), 4 waves. LN fused: each lane loads 32 fp32
// of its row (m = lane&15 selects row, quad selects channel chunk), stats
// reduced across quads via shfl_xor(16/32), normalized into bf16 A-frags.
// GEMM: A = Wfrag (m=ncol), B = xn rows -> D[ncol][p].
// Outputs: Qg/Kg [ih][j][d] uint2, Gg [ih][j][d] uint2 (sigmoid),
//          Vt_g [ih][d][k] scalar bf16 x4, BbF fp32 in attn-frag order.
// ---------------------------------------------------------------------------
__global__ __launch_bounds__(256) void proj_kernel(
    const float* __restrict__ x, const float* __restrict__ gamma, const float* __restrict__ beta,
    const ushort* __restrict__ Wfrag, const float* __restrict__ bg,
    ushort* __restrict__ Qg, ushort* __restrict__ Kg, ushort* __restrict__ Vtg,
    ushort* __restrict__ Gg, float* __restrict__ BbF)
{
    __shared__ ushort Bs[11 * 2048];
    const int t = threadIdx.x;
    const int wave = t >> 6, lane = t & 63, m = lane & 15, quad = lane >> 4;
    const int p0 = blockIdx.x * 64;
    const int arow = p0 + wave * 16 + m;

    // ---- fused LayerNorm into A-fragments ----
    float4 xa[4][2];
    float sum = 0.f, ssq = 0.f;
#pragma unroll
    for (int ks = 0; ks < 4; ++ks) {
        const float* rp = x + arow * 128 + ks * 32 + quad * 8;
        xa[ks][0] = ld4f(rp);
        xa[ks][1] = ld4f(rp + 4);
#pragma unroll
        for (int q4 = 0; q4 < 2; ++q4) {
            float4 v = xa[ks][q4];
            sum += v.x + v.y + v.z + v.w;
            ssq += v.x * v.x + v.y * v.y + v.z * v.z + v.w * v.w;
        }
    }
    sum += __shfl_xor(sum, 16); ssq += __shfl_xor(ssq, 16);
    sum += __shfl_xor(sum, 32); ssq += __shfl_xor(ssq, 32);
    const float mu   = sum * (1.f / 128.f);
    const float var  = ssq * (1.f / 128.f) - mu * mu;
    const float rstd = rsqrtf(var + 1e-5f);

    bf16x8 xf[4];
#pragma unroll
    for (int ks = 0; ks < 4; ++ks) {
        union { bf16x8 v; uint u[4]; } xu;
#pragma unroll
        for (int q4 = 0; q4 < 2; ++q4) {
            const int c = ks * 32 + quad * 8 + q4 * 4;
            float4 g4 = ld4f(gamma + c);
            float4 b4 = ld4f(beta + c);
            float4 v = xa[ks][q4];
            float n0 = (v.x - mu) * rstd * g4.x + b4.x;
            float n1 = (v.y - mu) * rstd * g4.y + b4.y;
            float n2 = (v.z - mu) * rstd * g4.z + b4.z;
            float n3 = (v.w - mu) * rstd * g4.w + b4.w;
            xu.u[q4 * 2]     = pk2(n0, n1);
            xu.u[q4 * 2 + 1] = pk2(n2, n3);
        }
        xf[ks] = xu.v;
    }

    const int p = arow;
    const int i = p >> 8, j2 = p & 255;

    for (int phase = 0; phase < 3; ++phase) {
        const int ctbase = phase * 11;
        __syncthreads();
        const uint4* src = (const uint4*)(Wfrag + ctbase * 2048);
        uint4* dst = (uint4*)Bs;
#pragma unroll
        for (int r = 0; r < 11; ++r) dst[r * 256 + t] = src[r * 256 + t];
        __syncthreads();

        for (int ctl = 0; ctl < 11; ++ctl) {
            const int ct = ctbase + ctl;
            f32x4 acc = (f32x4){0.f, 0.f, 0.f, 0.f};
#pragma unroll
            for (int ks = 0; ks < 4; ++ks) {
                bf16x8 wfr = ((const bf16x8*)Bs)[(ctl * 4 + ks) * 64 + lane];
                acc = __builtin_amdgcn_mfma_f32_16x16x32_bf16(wfr, xf[ks], acc, 0, 0, 0);
            }
            if (ct < 32) {
                const int cls = ct >> 3;
                const int npb = (ct & 7) * 16 + quad * 4;   // class-local col base
                const int hh = npb >> 5, d0 = npb & 31;
                if (cls == 2) {
                    // V transposed: Vtg[(i*4+hh)*32 + d][j2]
                    const int vb = ((i * 4 + hh) * 32 + d0) * 256 + j2;
#pragma unroll
                    for (int r = 0; r < 4; ++r)
                        Vtg[vb + r * 256] = f2bf(acc[r]);
                } else {
                    const int off = ((i * 4 + hh) * 256 + j2) * 32 + d0;
                    uint2 u;
                    if (cls == 3) {
                        float4 bg4 = ld4f(&bg[npb]);
                        float z0 = 1.f / (1.f + __expf(-(acc[0] + bg4.x)));
                        float z1 = 1.f / (1.f + __expf(-(acc[1] + bg4.y)));
                        float z2 = 1.f / (1.f + __expf(-(acc[2] + bg4.z)));
                        float z3 = 1.f / (1.f + __expf(-(acc[3] + bg4.w)));
                        u.x = pk2(z0, z1); u.y = pk2(z2, z3);
                        *(uint2*)(&Gg[off]) = u;
                    } else {
                        u.x = pk2(acc[0], acc[1]); u.y = pk2(acc[2], acc[3]);
                        if (cls == 0) *(uint2*)(&Qg[off]) = u;
                        else          *(uint2*)(&Kg[off]) = u;
                    }
                }
            } else if (quad == 0) {
                // bias cols: ncol = 512 + r -> h = r; fp32 scatter, attn-frag order
#pragma unroll
                for (int r = 0; r < 4; ++r) {
                    int addr = (((r * 16 + (i >> 4)) * 16 + (j2 >> 4)) * 64 +
                                ((j2 & 15) >> 2) * 16 + (i & 15)) * 4 + (j2 & 3);
                    BbF[addr] = acc[r];
                }
            }
        }
    }
}

// ---------------------------------------------------------------------------
// attn: grid 1024 = (i*4+h). 4 waves; wave = 64 q-rows. No __syncthreads.
// S^T = mfma(A=K, B=Q, acc=bias-frag fp32): row=k, col=j. P staged per-wave
// in LDS (stride-72). O^T = mfma(A=V^T-from-global, B=P): row=d, col=j ->
// packed G loads, packed gvals stores, per-lane 1/sum.
// LDS 36,864 B -> 4 blocks/CU.
// ---------------------------------------------------------------------------
__global__ __launch_bounds__(256) void attn_kernel(
    const ushort* __restrict__ Qg, const ushort* __restrict__ Kg, const ushort* __restrict__ Vtg,
    const ushort* __restrict__ Gg, const float* __restrict__ BbF, ushort* __restrict__ gvals)
{
    __shared__ ushort Pl[4][64 * 72];     // per-wave P [j][k-local 64], stride 72
    const int t = threadIdx.x;
    const int wave = t >> 6, lane = t & 63, m = lane & 15, quad = lane >> 4;
    const int ih = blockIdx.x, i = ih >> 2, h = ih & 3;

    const int j0 = wave * 64;
    bf16x8 qf[4];                          // B-frag: lane = j, elems = d
#pragma unroll
    for (int jt = 0; jt < 4; ++jt)
        qf[jt] = *(const bf16x8*)(Qg + ih * 8192 + (j0 + jt * 16 + m) * 32 + quad * 8);

    f32x4 O[4][2];                         // [jt][dt], row=d, col=j
    float lsum[4];
#pragma unroll
    for (int jt = 0; jt < 4; ++jt) {
        O[jt][0] = (f32x4){0.f, 0.f, 0.f, 0.f};
        O[jt][1] = (f32x4){0.f, 0.f, 0.f, 0.f};
        lsum[jt] = 0.f;
    }

    for (int kt2 = 0; kt2 < 4; ++kt2) {
        const int k0 = kt2 * 64;
        bf16x8 kf[4];                      // A-frag: lane = k_, elems = d
#pragma unroll
        for (int kk = 0; kk < 4; ++kk)
            kf[kk] = *(const bf16x8*)(Kg + ih * 8192 + (k0 + kk * 16 + m) * 32 + quad * 8);

#pragma unroll
        for (int jt = 0; jt < 4; ++jt) {
            const int jtg = wave * 4 + jt;
#pragma unroll
            for (int kk = 0; kk < 4; ++kk) {
                const int ktg = kt2 * 4 + kk;
                f32x4 bias = *(const f32x4*)(BbF + (((h * 16 + jtg) * 16 + ktg) * 64 + lane) * 4);
                f32x4 S = __builtin_amdgcn_mfma_f32_16x16x32_bf16(kf[kk], qf[jt], bias, 0, 0, 0);
                float pv0 = __expf(S[0]);
                float pv1 = __expf(S[1]);
                float pv2 = __expf(S[2]);
                float pv3 = __expf(S[3]);
                lsum[jt] += pv0 + pv1 + pv2 + pv3;
                uint2 u; u.x = pk2(pv0, pv1); u.y = pk2(pv2, pv3);
                *(uint2*)(&Pl[wave][(jt * 16 + m) * 72 + kk * 16 + quad * 4]) = u;
            }
        }
#pragma unroll
        for (int kc = 0; kc < 2; ++kc) {
            bf16x8 pf[4], vf[2];
#pragma unroll
            for (int jt = 0; jt < 4; ++jt)   // B-frag: lane = j, elems = k
                pf[jt] = *(const bf16x8*)(&Pl[wave][(jt * 16 + m) * 72 + kc * 32 + quad * 8]);
#pragma unroll
            for (int dt = 0; dt < 2; ++dt)   // A-frag from global: lane = d, elems = k
                vf[dt] = *(const bf16x8*)(Vtg + (ih * 32 + dt * 16 + m) * 256 + k0 + kc * 32 + quad * 8);
#pragma unroll
            for (int jt = 0; jt < 4; ++jt)
#pragma unroll
                for (int dt = 0; dt < 2; ++dt)
                    O[jt][dt] = __builtin_amdgcn_mfma_f32_16x16x32_bf16(
                        vf[dt], pf[jt], O[jt][dt], 0, 0, 0);
        }
    }

    // total row sums: partials live per-lane at j = lane&15; reduce across quads
#pragma unroll
    for (int jt = 0; jt < 4; ++jt) {
        float s = lsum[jt];
        s += __shfl_xor(s, 16);
        s += __shfl_xor(s, 32);
        lsum[jt] = 1.f / s;
    }

    // epilogue: gvals[(i*256+j)][h*32+d] = G * O / sum  (d = quad*4+r + dt*16)
#pragma unroll
    for (int jt = 0; jt < 4; ++jt) {
        const int j = j0 + jt * 16 + m;
        const float rl = lsum[jt];
#pragma unroll
        for (int dt = 0; dt < 2; ++dt) {
            const int d0 = dt * 16 + quad * 4;
            ushort4 gv = *(const ushort4*)(&Gg[ih * 8192 + j * 32 + d0]);
            float v0 = O[jt][dt][0] * rl * bf2f(gv.x);
            float v1 = O[jt][dt][1] * rl * bf2f(gv.y);
            float v2 = O[jt][dt][2] * rl * bf2f(gv.z);
            float v3 = O[jt][dt][3] * rl * bf2f(gv.w);
            uint2 u; u.x = pk2(v0, v1); u.y = pk2(v2, v3);
            *(uint2*)(&gvals[(i * 256 + j) * 128 + h * 32 + d0]) = u;
        }
    }
}

// ---------------------------------------------------------------------------
// oproj: A = WoFrag, B = gvals rows -> D[ncol][p]; float4 stores + bo.
// ---------------------------------------------------------------------------
__global__ __launch_bounds__(256) void oproj_kernel(
    const ushort* __restrict__ gvals, const ushort* __restrict__ WoFrag,
    const float* __restrict__ bo, float* __restrict__ out)
{
    __shared__ ushort Bs[8 * 2048];
    const int t = threadIdx.x;
    const int wave = t >> 6, lane = t & 63, m = lane & 15, quad = lane >> 4;
    const int p0 = blockIdx.x * 64;
    {
        const uint4* src = (const uint4*)WoFrag;
        uint4* dst = (uint4*)Bs;
#pragma unroll
        for (int r = 0; r < 8; ++r) dst[r * 256 + t] = src[r * 256 + t];
    }
    bf16x8 gf[4];
    const int p = p0 + wave * 16 + m;
#pragma unroll
    for (int ks = 0; ks < 4; ++ks)
        gf[ks] = *(const bf16x8*)(gvals + p * 128 + ks * 32 + quad * 8);
    __syncthreads();

#pragma unroll
    for (int ct = 0; ct < 8; ++ct) {
        f32x4 acc = (f32x4){0.f, 0.f, 0.f, 0.f};
#pragma unroll
        for (int ks = 0; ks < 4; ++ks) {
            bf16x8 wfr = ((const bf16x8*)Bs)[(ct * 4 + ks) * 64 + lane];
            acc = __builtin_amdgcn_mfma_f32_16x16x32_bf16(wfr, gf[ks], acc, 0, 0, 0);
        }
        const int c0 = ct * 16 + quad * 4;
        float4 bov = ld4f(&bo[c0]);
        float4 v = make_float4(acc[0] + bov.x, acc[1] + bov.y,
                               acc[2] + bov.z, acc[3] + bov.w);
        *(float4*)(&out[p * 128 + c0]) = v;
    }
}

// ---------------------------------------------------------------------------
extern "C" void kernel_launch(void* const* d_in, const int* in_sizes, int n_in,
                              void* d_out, int out_size, void* d_ws, size_t ws_size,
                              hipStream_t stream) {
    const float* x     = (const float*)d_in[0];
    const float* gamma = (const float*)d_in[1];
    const float* beta  = (const float*)d_in[2];
    const float* Wq    = (const float*)d_in[3];
    const float* Wk    = (const float*)d_in[4];
    const float* Wv    = (const float*)d_in[5];
    const float* Wb    = (const float*)d_in[6];
    const float* Wg    = (const float*)d_in[7];
    const float* bg    = (const float*)d_in[8];
    const float* Wo    = (const float*)d_in[9];
    const float* bo    = (const float*)d_in[10];

    ushort* ws     = (ushort*)d_ws;
    ushort* Wfrag  = ws;                       // 67584
    ushort* WoFrag = Wfrag + 67584;            // 16384
    ushort* Qg     = WoFrag + 16384;           // 8388608 each
    ushort* Kg     = Qg + 8388608;             // [ih][j][d]
    ushort* Vtg    = Kg + 8388608;             // [ih][d][k]
    ushort* Gg     = Vtg + 8388608;            // [ih][j][d]
    ushort* gvals  = Gg + 8388608;             // [p][128]
    float*  BbF    = (float*)(gvals + 8388608);  // 262144 fp32, attn-frag order
    // total ~85 MB of d_ws

    prep_kernel<<<328, 256, 0, stream>>>(Wq, Wk, Wv, Wb, Wg, Wo, Wfrag, WoFrag);
    proj_kernel<<<1024, 256, 0, stream>>>(x, gamma, beta, Wfrag, bg, Qg, Kg, Vtg, Gg, BbF);
    attn_kernel<<<1024, 256, 0, stream>>>(Qg, Kg, Vtg, Gg, BbF, gvals);
    oproj_kernel<<<1024, 256, 0, stream>>>(gvals, WoFrag, bo, (float*)d_out);
}